// Round 1
// 254.519 us; speedup vs baseline: 1.0191x; 1.0191x over previous
//
#include <hip/hip_runtime.h>
#include <math.h>

// Problem constants (reference: x_l [16, 1, 1536, 1536] fp32, PATCH=3, ALPHA=1)
#define IMG_W 1536
#define IMG_H 1536
#define NIMG  16
#define RPB 8                       // output rows per thread
#define NROWS (RPB + 2)             // loaded rows (incl. vertical halo)

typedef float f32x4 __attribute__((ext_vector_type(4)));

// out(h,w) = sum_k v_k*exp(-v_k) / sum_k exp(-v_k) over the 3x3 zero-padded
// neighborhood (the "-x^2" shift cancels in softmax; padded taps: e=1, ve=0).
//
// R5 change vs R4: rocprof showed VGPR_Count=44 -> the compiler re-sank the
// phase-1 loads (needs >=60 VGPRs to hold them), leaving ~3-4 loads in flight
// per wave -> latency-bound at 2.75 TB/s. Also every row's critical path went
// through 8 ds_permute shuffles + 2 divergent exec-mask halo loads.
// Fix: (a) each lane loads its OWN halo scalars rp[-1]/rp[4] (same cache
// lines, L1-hit) and recomputes the 2 halo exps -> zero ds ops, near-uniform
// predication; (b) a sched_barrier(0) between the load burst and compute pins
// all 30 loads (~15 KB/wave) above first use so they stay in flight.
__global__ __launch_bounds__(128)
void WeightedAverage_55551107006568_kernel(const float* __restrict__ x,
                                           float* __restrict__ out) {
    const int g  = blockIdx.x * 128 + threadIdx.x;   // column-group index
    const int w0 = g << 2;                           // first owned column
    const int h0 = blockIdx.y * RPB;
    const size_t plane = (size_t)blockIdx.z * ((size_t)IMG_H * IMG_W);
    const float* xp = x + plane;
    float* op = out + plane;

    // ---- phase 1: issue ALL loads (30 outstanding vmcnt items) ----
    f32x4 m[NROWS];
    float hl[NROWS], hr[NROWS];
    const bool lok = (w0 > 0);            // col w0-1 exists (false only for g==0)
    const bool rok = (w0 + 4 < IMG_W);    // col w0+4 exists (false only for last g)
#pragma unroll
    for (int i = 0; i < NROWS; ++i) {
        const int r = h0 - 1 + i;                    // block-uniform row index
        f32x4 mm = {0.f, 0.f, 0.f, 0.f};
        float hlv = 0.f, hrv = 0.f;                  // 0 -> e=1, ve=0 (pad)
        if (r >= 0 && r < IMG_H) {
            const float* rp = xp + (size_t)r * IMG_W + w0;
            mm = *(const f32x4*)rp;
            if (lok) hlv = rp[-1];
            if (rok) hrv = rp[4];
        }
        m[i] = mm; hl[i] = hlv; hr[i] = hrv;
    }
    // Nothing (especially not the loads above) may cross this point.
    __builtin_amdgcn_sched_barrier(0);

    // ---- phase 2: per-row horizontal 3-sums, rolling vertical 3-sum ----
    float hE[3][4], hVE[3][4];
#pragma unroll
    for (int i = 0; i < NROWS; ++i) {
        const int r = h0 - 1 + i;
        const int s = i % 3;
        if (r < 0 || r >= IMG_H) {
            // fully padded row: all taps v=0 -> e=1 -> hE=3, hVE=0
#pragma unroll
            for (int p = 0; p < 4; ++p) { hE[s][p] = 3.f; hVE[s][p] = 0.f; }
        } else {
            const f32x4 mm = m[i];
            // halo columns: own loads (0 when outside image -> e=1, v=0 = pad)
            const float eL = __expf(-hl[i]), vL = hl[i] * eL;
            const float e0 = __expf(-mm.x),  v0 = mm.x * e0;
            const float e1 = __expf(-mm.y),  v1 = mm.y * e1;
            const float e2 = __expf(-mm.z),  v2 = mm.z * e2;
            const float e3 = __expf(-mm.w),  v3 = mm.w * e3;
            const float eR = __expf(-hr[i]), vR = hr[i] * eR;
            hE[s][0] = eL + e0 + e1;  hVE[s][0] = vL + v0 + v1;
            hE[s][1] = e0 + e1 + e2;  hVE[s][1] = v0 + v1 + v2;
            hE[s][2] = e1 + e2 + e3;  hVE[s][2] = v1 + v2 + v3;
            hE[s][3] = e2 + e3 + eR;  hVE[s][3] = v2 + v3 + vR;
        }

        if (i >= 2) {
            const int ro = h0 + i - 2;               // output row
            f32x4 o;
#pragma unroll
            for (int p = 0; p < 4; ++p) {
                const float den = hE[0][p] + hE[1][p] + hE[2][p];
                const float num = hVE[0][p] + hVE[1][p] + hVE[2][p];
                o[p] = __fdividef(num, den);
            }
            // write-once output: nontemporal so it doesn't evict input from L2/L3
            __builtin_nontemporal_store(o, (f32x4*)(op + (size_t)ro * IMG_W + w0));
        }
    }
}

extern "C" void kernel_launch(void* const* d_in, const int* in_sizes, int n_in,
                              void* d_out, int out_size, void* d_ws, size_t ws_size,
                              hipStream_t stream) {
    const float* x = (const float*)d_in[0];
    float* out = (float*)d_out;
    dim3 grid(IMG_W / (128 * 4), IMG_H / RPB, NIMG);   // (3, 192, 16)
    dim3 block(128, 1, 1);
    WeightedAverage_55551107006568_kernel<<<grid, block, 0, stream>>>(x, out);
}